// Round 1
// baseline (231.317 us; speedup 1.0000x reference)
//
#include <hip/hip_runtime.h>

// Pixel-unshuffle 2x2 (space-to-depth), fp32.
// in : [32, 1, 2048, 2048]  out : [32, 4, 1024, 1024]
// out[b][2*(h&1) + (w&1)][h/2][w/2] = in[b][0][h][w]
//
// Each work item: 8 consecutive input floats (2x float4, coalesced load)
//   -> evens (w0,w0+2,w0+4,w0+6) = contiguous float4 at j=w0/2 in plane cbase
//   -> odds                      = contiguous float4 at j=w0/2 in plane cbase+1
// Both stores are coalesced across the wave.

__global__ __launch_bounds__(256) void pixel_unshuffle_kernel(
    const float4* __restrict__ in4, float4* __restrict__ out4, int n_items) {
    const int stride = gridDim.x * blockDim.x;
    for (int t = blockIdx.x * blockDim.x + threadIdx.x; t < n_items; t += stride) {
        const int wi  = t & 255;   // item within row (256 items * 8 floats = 2048)
        const int row = t >> 8;    // b*2048 + h
        const int h   = row & 2047;
        const int b   = row >> 11;

        const float4 a = in4[2 * t + 0];
        const float4 c = in4[2 * t + 1];

        const float4 ev = make_float4(a.x, a.z, c.x, c.z);
        const float4 od = make_float4(a.y, a.w, c.y, c.w);

        const int i     = h >> 1;
        const int cbase = (h & 1) << 1;
        // float4-unit offsets: plane = 1024*1024 floats = 262144 float4,
        // out row = 1024 floats = 256 float4
        const int obase = (((b << 2) + cbase) << 18) + (i << 8) + wi;

        out4[obase]          = ev;   // channel cbase
        out4[obase + 262144] = od;   // channel cbase + 1
    }
}

extern "C" void kernel_launch(void* const* d_in, const int* in_sizes, int n_in,
                              void* d_out, int out_size, void* d_ws, size_t ws_size,
                              hipStream_t stream) {
    const float4* in4 = (const float4*)d_in[0];
    float4* out4      = (float4*)d_out;

    const int n_items = 32 * 2048 * 2048 / 8;  // 16,777,216 items of 8 floats
    const int block   = 256;
    const int grid    = 2048;  // grid-stride; ~8 blocks/CU on 256 CUs

    pixel_unshuffle_kernel<<<grid, block, 0, stream>>>(in4, out4, n_items);
}

// Round 2
// 209.424 us; speedup vs baseline: 1.1045x; 1.1045x over previous
//
#include <hip/hip_runtime.h>

// Pixel-unshuffle 2x2 (space-to-depth), fp32.
// in : [32, 1, 2048, 2048]  out : [32, 4, 1024, 1024]
// out[b][2*(h&1) + (w&1)][h/2][w/2] = in[b][0][h][w]
//
// R2: 2 items/thread/iteration (4 loads in flight before stores) +
// non-temporal load/store hints (both streams are touch-once, >> 32MB L2).

typedef float f32x4 __attribute__((ext_vector_type(4)));

__device__ __forceinline__ void unshuffle_item(
    int t, f32x4 a, f32x4 c, f32x4* __restrict__ out4) {
    const int wi  = t & 255;   // item within row (256 items * 8 floats = 2048)
    const int row = t >> 8;    // b*2048 + h
    const int h   = row & 2047;
    const int b   = row >> 11;

    f32x4 ev, od;
    ev.x = a.x; ev.y = a.z; ev.z = c.x; ev.w = c.z;
    od.x = a.y; od.y = a.w; od.z = c.y; od.w = c.w;

    const int i     = h >> 1;
    const int cbase = (h & 1) << 1;
    // float4-unit offsets: out plane = 262144 float4, out row = 256 float4
    const int obase = (((b << 2) + cbase) << 18) + (i << 8) + wi;

    __builtin_nontemporal_store(ev, out4 + obase);           // channel cbase
    __builtin_nontemporal_store(od, out4 + obase + 262144);  // channel cbase+1
}

__global__ __launch_bounds__(256) void pixel_unshuffle_kernel(
    const f32x4* __restrict__ in4, f32x4* __restrict__ out4, int n_items) {
    const int tpb  = 256;
    const int span = gridDim.x * tpb * 2;  // items covered per sweep
    for (int base = blockIdx.x * tpb * 2 + threadIdx.x; base < n_items;
         base += span) {
        const int t0 = base;
        const int t1 = base + tpb;  // n_items % span == 0 for this shape

        // Issue all 4 loads before any dependent use.
        const f32x4 a0 = __builtin_nontemporal_load(in4 + 2 * t0);
        const f32x4 c0 = __builtin_nontemporal_load(in4 + 2 * t0 + 1);
        const f32x4 a1 = __builtin_nontemporal_load(in4 + 2 * t1);
        const f32x4 c1 = __builtin_nontemporal_load(in4 + 2 * t1 + 1);

        unshuffle_item(t0, a0, c0, out4);
        unshuffle_item(t1, a1, c1, out4);
    }
}

extern "C" void kernel_launch(void* const* d_in, const int* in_sizes, int n_in,
                              void* d_out, int out_size, void* d_ws, size_t ws_size,
                              hipStream_t stream) {
    const f32x4* in4 = (const f32x4*)d_in[0];
    f32x4* out4      = (f32x4*)d_out;

    const int n_items = 32 * 2048 * 2048 / 8;  // 16,777,216 items of 8 floats
    const int block   = 256;
    const int grid    = 2048;  // 16 sweeps of the grid-stride loop

    pixel_unshuffle_kernel<<<grid, block, 0, stream>>>(in4, out4, n_items);
}

// Round 3
// 202.009 us; speedup vs baseline: 1.1451x; 1.0367x over previous
//
#include <hip/hip_runtime.h>

// Pixel-unshuffle 2x2 (space-to-depth), fp32.
// in : [32, 1, 2048, 2048]  out : [32, 4, 1024, 1024]
// out[b][2*(h&1) + (w&1)][h/2][w/2] = in[b][0][h][w]
//
// R3: 4 items/thread/iteration -> 8 float4 loads in flight before any store.
// Loads+stores share vmcnt (FIFO); deeper load batches amortize the
// mixed-counter serialization between iterations. nt on both sides
// (both streams touch-once, >> 32 MB L2 / 256 MB L3 working set).

typedef float f32x4 __attribute__((ext_vector_type(4)));

__device__ __forceinline__ void unshuffle_item(
    int t, f32x4 a, f32x4 c, f32x4* __restrict__ out4) {
    const int wi  = t & 255;   // item within row (256 items * 8 floats = 2048)
    const int row = t >> 8;    // b*2048 + h
    const int h   = row & 2047;
    const int b   = row >> 11;

    f32x4 ev, od;
    ev.x = a.x; ev.y = a.z; ev.z = c.x; ev.w = c.z;
    od.x = a.y; od.y = a.w; od.z = c.y; od.w = c.w;

    const int i     = h >> 1;
    const int cbase = (h & 1) << 1;
    // float4-unit offsets: out plane = 262144 float4, out row = 256 float4
    const int obase = (((b << 2) + cbase) << 18) + (i << 8) + wi;

    __builtin_nontemporal_store(ev, out4 + obase);           // channel cbase
    __builtin_nontemporal_store(od, out4 + obase + 262144);  // channel cbase+1
}

__global__ __launch_bounds__(256) void pixel_unshuffle_kernel(
    const f32x4* __restrict__ in4, f32x4* __restrict__ out4, int n_items) {
    const int tpb  = 256;
    const int span = gridDim.x * tpb * 4;  // items covered per sweep
    for (int base = blockIdx.x * tpb * 4 + threadIdx.x; base < n_items;
         base += span) {
        const int t0 = base;
        const int t1 = base + tpb;      // n_items % span == 0 for this shape
        const int t2 = base + 2 * tpb;
        const int t3 = base + 3 * tpb;

        // Issue all 8 loads before any dependent use.
        const f32x4 a0 = __builtin_nontemporal_load(in4 + 2 * t0);
        const f32x4 c0 = __builtin_nontemporal_load(in4 + 2 * t0 + 1);
        const f32x4 a1 = __builtin_nontemporal_load(in4 + 2 * t1);
        const f32x4 c1 = __builtin_nontemporal_load(in4 + 2 * t1 + 1);
        const f32x4 a2 = __builtin_nontemporal_load(in4 + 2 * t2);
        const f32x4 c2 = __builtin_nontemporal_load(in4 + 2 * t2 + 1);
        const f32x4 a3 = __builtin_nontemporal_load(in4 + 2 * t3);
        const f32x4 c3 = __builtin_nontemporal_load(in4 + 2 * t3 + 1);

        unshuffle_item(t0, a0, c0, out4);
        unshuffle_item(t1, a1, c1, out4);
        unshuffle_item(t2, a2, c2, out4);
        unshuffle_item(t3, a3, c3, out4);
    }
}

extern "C" void kernel_launch(void* const* d_in, const int* in_sizes, int n_in,
                              void* d_out, int out_size, void* d_ws, size_t ws_size,
                              hipStream_t stream) {
    const f32x4* in4 = (const f32x4*)d_in[0];
    f32x4* out4      = (f32x4*)d_out;

    const int n_items = 32 * 2048 * 2048 / 8;  // 16,777,216 items of 8 floats
    const int block   = 256;
    const int grid    = 2048;  // 8 sweeps of the grid-stride loop

    pixel_unshuffle_kernel<<<grid, block, 0, stream>>>(in4, out4, n_items);
}